// Round 3
// baseline (7662.529 us; speedup 1.0000x reference)
//
#include <hip/hip_runtime.h>
#include <math.h>
#include <type_traits>

// Fused MLP head with BINARY output gated by a per-row rank-k comparison.
// Hypothesis (r3): harness's np reference is float64 end-to-end; any fp32
// rounding anywhere flips ~1-3 of 16384 rows => absmax 1.0. So: fp64
// storage + accumulation everywhere. Correctness probe, not speed.
//
// ws-size-proof: B and H chunked host-side (arithmetic only, capture-safe).
//   ws layout per chunk: L[Bc][F] fp64 logits | h64[Bc][Hc] fp64 hidden.

#define BM 128
#define BN 128
#define BK 16

// out64 = epilogue(A @ W^T), A:(M,K) TA ld=lda, W:(N,*) fp32 ld=ldw.
// MODE 0: relu(acc+bias)  -> out64   (GEMM1 -> h64 chunk)
// MODE 1: acc+bias        -> out64   (GEMM2, first H-chunk)
// MODE 2: out64 += acc              (GEMM2, later H-chunks)
template<typename TA, int MODE>
__global__ __launch_bounds__(256, 1) void gemm64(
    const TA* __restrict__ A, int lda,
    const float* __restrict__ W, int ldw,
    const float* __restrict__ bias,
    double* __restrict__ out64, int N, int K)
{
    __shared__ double As[BK][BM + 2];
    __shared__ double Bs[BK][BN + 2];
    const int t  = threadIdx.x;
    const int tm = t >> 4;          // 0..15
    const int tn = t & 15;          // 0..15
    const size_t bm = blockIdx.x;
    const size_t bn = blockIdx.y;
    const TA*    Ab = A + bm * BM * (size_t)lda;
    const float* Wb = W + bn * BN * (size_t)ldw;

    double acc[8][8] = {};

    for (int k0 = 0; k0 < K; k0 += BK) {
        #pragma unroll
        for (int i = 0; i < 2; ++i) {
            int f   = t + i * 256;       // 0..511
            int row = f >> 2;            // 0..127
            int kc  = (f & 3) << 2;      // 0,4,8,12
            if constexpr (std::is_same<TA, double>::value) {
                double2 v0 = *(const double2*)(Ab + (size_t)row * lda + k0 + kc);
                double2 v1 = *(const double2*)(Ab + (size_t)row * lda + k0 + kc + 2);
                As[kc + 0][row] = v0.x; As[kc + 1][row] = v0.y;
                As[kc + 2][row] = v1.x; As[kc + 3][row] = v1.y;
            } else {
                float4 va = *(const float4*)(Ab + (size_t)row * lda + k0 + kc);
                As[kc + 0][row] = (double)va.x; As[kc + 1][row] = (double)va.y;
                As[kc + 2][row] = (double)va.z; As[kc + 3][row] = (double)va.w;
            }
            float4 vb = *(const float4*)(Wb + (size_t)row * ldw + k0 + kc);
            Bs[kc + 0][row] = (double)vb.x; Bs[kc + 1][row] = (double)vb.y;
            Bs[kc + 2][row] = (double)vb.z; Bs[kc + 3][row] = (double)vb.w;
        }
        __syncthreads();
        #pragma unroll
        for (int k = 0; k < BK; ++k) {
            double a[8], b[8];
            #pragma unroll
            for (int i = 0; i < 4; ++i) {
                *(double2*)&a[i * 2] = *(const double2*)&As[k][tm * 8 + i * 2];
                *(double2*)&b[i * 2] = *(const double2*)&Bs[k][tn * 8 + i * 2];
            }
            #pragma unroll
            for (int i = 0; i < 8; ++i)
                #pragma unroll
                for (int j = 0; j < 8; ++j)
                    acc[i][j] = fma(a[i], b[j], acc[i][j]);
        }
        __syncthreads();
    }

    double bv[8];
    if (MODE != 2) {
        #pragma unroll
        for (int j = 0; j < 8; ++j) bv[j] = (double)bias[bn * BN + tn * 8 + j];
    }

    #pragma unroll
    for (int i = 0; i < 8; ++i) {
        size_t row  = bm * BM + (size_t)tm * 8 + i;
        size_t base = row * (size_t)N + bn * BN + tn * 8;
        #pragma unroll
        for (int j = 0; j < 8; ++j) {
            double v = acc[i][j];
            if (MODE == 0) out64[base + j] = fmax(v + bv[j], 0.0);
            if (MODE == 1) out64[base + j] = v + bv[j];
            if (MODE == 2) out64[base + j] += v;
        }
    }
}

// One wave per row of ncols(=512) fp64 logits: sigmoid in fp64, iterative
// top-k extraction with (value,index) tie-break (top_k multiset semantics),
// gate (s >= kth && s > 0.2) in fp64, write fp32 0/1.
__global__ __launch_bounds__(256) void topk64_kernel(
    const double* __restrict__ L, float* __restrict__ O, int ncols,
    const int* __restrict__ kp)
{
    const int wave = threadIdx.x >> 6;
    const int lane = threadIdx.x & 63;
    const int k = *kp;
    const size_t row = (size_t)blockIdx.x * 4 + wave;
    const double* Lr = L + row * (size_t)ncols;

    double v[8];
    #pragma unroll
    for (int j = 0; j < 8; ++j) {
        double l = Lr[lane * 8 + j];
        v[j] = 1.0 / (1.0 + exp(-l));
    }
    double w[8];
    #pragma unroll
    for (int j = 0; j < 8; ++j) w[j] = v[j];

    double kth = -1.0e300;
    for (int it = 0; it < k; ++it) {
        double mv = w[0]; int mj = 0;
        #pragma unroll
        for (int j = 1; j < 8; ++j)
            if (w[j] > mv) { mv = w[j]; mj = j; }
        int mi = lane * 8 + mj;
        #pragma unroll
        for (int off = 32; off; off >>= 1) {
            double ov = __shfl_xor(mv, off);
            int    oi = __shfl_xor(mi, off);
            if (ov > mv || (ov == mv && oi < mi)) { mv = ov; mi = oi; }
        }
        kth = mv;
        if ((mi >> 3) == lane) w[mi & 7] = -1.0e300;
    }

    float o[8];
    #pragma unroll
    for (int j = 0; j < 8; ++j)
        o[j] = (v[j] >= kth && v[j] > 0.2) ? 1.0f : 0.0f;
    float* Op = O + row * (size_t)ncols + lane * 8;
    *(float4*)&Op[0] = *(const float4*)&o[0];
    *(float4*)&Op[4] = *(const float4*)&o[4];
}

extern "C" void kernel_launch(void* const* d_in, const int* in_sizes, int n_in,
                              void* d_out, int out_size, void* d_ws, size_t ws_size,
                              hipStream_t stream) {
    const float* inp = (const float*)d_in[0];
    const float* W1  = (const float*)d_in[1];
    const float* b1  = (const float*)d_in[2];
    const float* W2  = (const float*)d_in[3];
    const float* b2  = (const float*)d_in[4];
    const int*   kp  = (const int*)d_in[5];

    const int H = in_sizes[2];              // 2048
    const int F = in_sizes[4];              // 512
    const int D = in_sizes[1] / H;          // 4096
    const int B = in_sizes[0] / D;          // 16384
    float* out = (float*)d_out;

    // Chunk sizing (host arithmetic only): L[Bc][F] + h64[Bc][Hc], fp64.
    int Hc = H;
    int Bc = 0;
    for (;;) {
        size_t perRow = (size_t)F * 8 + (size_t)Hc * 8;
        Bc = (int)((ws_size / perRow) / BM) * BM;
        if (Bc >= BM || Hc <= BM) break;
        Hc >>= 1;
    }
    if (Bc < BM) Bc = BM;
    if (Bc > B)  Bc = B;

    double* L   = (double*)d_ws;                 // Bc x F
    double* h64 = L + (size_t)Bc * F;            // Bc x Hc

    for (int b0 = 0; b0 < B; b0 += Bc) {
        int bc = (B - b0 < Bc) ? (B - b0) : Bc;
        for (int h0 = 0; h0 < H; h0 += Hc) {
            int hc = (H - h0 < Hc) ? (H - h0) : Hc;
            // GEMM1 chunk: h64[bc][hc] = relu64(inp[b0..] @ W1[h0..]^T + b1[h0..])
            gemm64<float, 0><<<dim3(bc / BM, hc / BN), 256, 0, stream>>>(
                inp + (size_t)b0 * D, D, W1 + (size_t)h0 * D, D, b1 + h0,
                h64, hc, D);
            // GEMM2 chunk: L[bc][F] (init|+=) h64 @ W2[:, h0..]^T (+ b2)
            if (h0 == 0)
                gemm64<double, 1><<<dim3(bc / BM, F / BN), 256, 0, stream>>>(
                    h64, hc, W2 + h0, H, b2, L, F, hc);
            else
                gemm64<double, 2><<<dim3(bc / BM, F / BN), 256, 0, stream>>>(
                    h64, hc, W2 + h0, H, b2, L, F, hc);
        }
        topk64_kernel<<<bc / 4, 256, 0, stream>>>(L, out + (size_t)b0 * F, F, kp);
    }
}